// Round 3
// baseline (748.765 us; speedup 1.0000x reference)
//
#include <hip/hip_runtime.h>
#include <hip/hip_cooperative_groups.h>

namespace cg = cooperative_groups;

// SparseAffinity_Propagate: CSPN-style 8-neighbor propagation, 24 iterations.
// B=8, H=W=768. Offsets (dy,dx): (-5,0)(-1,0)(0,5)(0,1)(5,0)(1,0)(0,-5)(0,-1)
//
// R0: fused form  result = sum_c (A*w_c) * prev[p+off_c] + Bias
// R1: w fp16 (16 B/px), bias fp32.
// R2: 4 px/thread, aligned 16B vectors.
// R3: batch->XCD partition (b = L&7): prev/next XCD-local.  948 -> 761 us.
// R4: w j-plane layout (dense 64B lines).  761 -> 748 us (writes now ideal,
//     but time unmoved -> request granularity was NOT the wall).
// R5: PERSISTENT cooperative kernel. The structural problem: w (75.5 MB) and
//     bias (18.9 MB) are invariant across the 24 steps but get re-streamed
//     from L3 every step (132 MB/step @ ~4.8 TB/s = 27 us/step). One
//     cooperative launch keeps bias in REGISTERS (20 VGPR/thread) and 44% of
//     w in LDS (32 KB/block, 4 blocks/CU) for all 24 iterations ->
//     ~80 MB/step, plus 25 launches -> 1. grid.sync() between iterations.
//     Fallback to the R4 multi-launch path if cooperative launch can't run.

#define HH 768
#define WW 768
#define BATCH 8
#define PLANE (HH * WW)           // 589824
#define TOTAL (BATCH * PLANE)     // 4718592
#define NG (TOTAL / 4)            // 1179648 pixel-groups
#define NITER 24

// persistent-kernel geometry
#define PBLOCKS 1024              // 4 blocks/CU x 256 CUs
#define PTHREADS 256
#define RPB 6                     // rows per block: 768 rows / 128 bands
#define GPR 192                   // 4-px groups per row
#define GPB (RPB * GPR)           // 1152 groups per block
#define NCHUNK 5                  // ceil(1152 / 256): chunks 0..3 full, 4 half
#define LDSC 2                    // chunks cached in LDS (2 x 16 KB = 32 KB)
#define GLOB_GPB (GPB - LDSC * PTHREADS)      // 640 groups -> global
#define NGW ((size_t)PBLOCKS * GLOB_GPB)      // 655360 groups per j-plane

#define DYS {-5, -1, 0, 0, 5, 1, 0, 0}
#define DXS {0, 0, 5, 1, 0, 0, -5, -1}

typedef _Float16 half8 __attribute__((ext_vector_type(8)));
typedef float f4 __attribute__((ext_vector_type(4)));

__device__ __forceinline__ f4 ldf4(const float* p) { return *(const f4*)p; }
// clamped-address + value-select: address is always in-bounds, value masked.
__device__ __forceinline__ f4 sel4(int c, f4 v) { return c ? v : (f4)0.f; }

// ===========================================================================
// R5 persistent kernel: precompute phase + 24 propagation steps, one launch.
// Block L: batch = L&7 (XCD partition), row band = (L>>3)*6 .. +6.
// Thread owns groups gl = k*256+tid, k=0..4 (k=4: tid<128).
// ===========================================================================
__global__ __launch_bounds__(PTHREADS, 4) void persist_kernel(
    const float* __restrict__ g,       // (B,8,H,W)
    const float* __restrict__ blur,    // (B,1,H,W)
    const float* __restrict__ sparse,  // (B,1,H,W)
    half8* __restrict__ wg,            // 4 j-planes x NGW (chunks 2..4 only)
    float* __restrict__ r0,            // ping
    float* __restrict__ r1,            // pong
    float* __restrict__ out)           // final output (B,1,H,W)
{
    __shared__ half8 lds_w[4][LDSC * PTHREADS];   // 32 KB: w for chunks 0,1

    cg::grid_group grid = cg::this_grid();

    const int L       = blockIdx.x;
    const int batch   = L & 7;
    const int band    = L >> 3;
    const int rowbase = band * RPB;
    const int tid     = threadIdx.x;
    const float* gb   = g + (size_t)batch * 8 * PLANE;

    f4 bias_r[NCHUNK];   // all indices compile-time (loops fully unrolled)

    // ---------------- precompute phase: w -> LDS/global, bias -> regs -----
#pragma unroll
    for (int k = 0; k < NCHUNK; ++k) {
        bias_r[k] = (f4)0.f;
        const int gl = k * PTHREADS + tid;
        if (gl < GPB) {
            const int yo   = gl / GPR;
            const int xg   = gl - yo * GPR;
            const int y    = rowbase + yo;
            const int x0   = 4 * xg;
            const int rowb = y * WW;
            const int pidx = batch * PLANE + rowb + x0;

            f4 wv[8];
            if (x0 >= 8 && x0 <= 756) {
                const int ya = (y >= 5)      ? y - 5 : y;
                const int yb = (y >= 1)      ? y - 1 : y;
                const int yc = (y <= HH - 6) ? y + 5 : y;
                const int yd = (y <= HH - 2) ? y + 1 : y;
                wv[0] = sel4(y >= 5,      ldf4(gb + 0 * PLANE + ya * WW + x0));
                wv[1] = sel4(y >= 1,      ldf4(gb + 1 * PLANE + yb * WW + x0));
                wv[4] = sel4(y <= HH - 6, ldf4(gb + 4 * PLANE + yc * WW + x0));
                wv[5] = sel4(y <= HH - 2, ldf4(gb + 5 * PLANE + yd * WW + x0));
                {   // c=2, dx=+5
                    f4 a  = ldf4(gb + 2 * PLANE + rowb + x0 + 4);
                    f4 bq = ldf4(gb + 2 * PLANE + rowb + x0 + 8);
                    wv[2] = f4{a[1], a[2], a[3], bq[0]};
                }
                {   // c=3, dx=+1
                    f4 a  = ldf4(gb + 3 * PLANE + rowb + x0);
                    f4 bq = ldf4(gb + 3 * PLANE + rowb + x0 + 4);
                    wv[3] = f4{a[1], a[2], a[3], bq[0]};
                }
                {   // c=6, dx=-5
                    f4 a  = ldf4(gb + 6 * PLANE + rowb + x0 - 8);
                    f4 bq = ldf4(gb + 6 * PLANE + rowb + x0 - 4);
                    wv[6] = f4{a[3], bq[0], bq[1], bq[2]};
                }
                {   // c=7, dx=-1
                    f4 a  = ldf4(gb + 7 * PLANE + rowb + x0 - 4);
                    f4 bq = ldf4(gb + 7 * PLANE + rowb + x0);
                    wv[7] = f4{a[3], bq[0], bq[1], bq[2]};
                }
            } else {
                const int dy[8] = DYS;
                const int dx[8] = DXS;
#pragma unroll
                for (int c = 0; c < 8; ++c) {
#pragma unroll
                    for (int j = 0; j < 4; ++j) {
                        int yy = y + dy[c];
                        int xx = x0 + j + dx[c];
                        float v = 0.f;
                        if (yy >= 0 && yy < HH && xx >= 0 && xx < WW)
                            v = gb[c * PLANE + yy * WW + xx];
                        wv[c][j] = v;
                    }
                }
            }

            f4 raw = ldf4(blur + pidx);
            f4 sd  = ldf4(sparse + pidx);
            f4 bout;
#pragma unroll
            for (int j = 0; j < 4; ++j) {
                float abssum = 0.f;
#pragma unroll
                for (int c = 0; c < 8; ++c) abssum += fabsf(wv[c][j]);
                float inv = 1.f / fmaxf(abssum, 1e-6f);
                float gs = 0.f;
#pragma unroll
                for (int c = 0; c < 8; ++c) gs += wv[c][j] * inv;
                float s = sd[j];
                float m = (s > 0.f) ? 1.f : ((s < 0.f) ? -1.f : 0.f);
                float A = 1.f - m;
                bout[j] = (A * (1.f - gs) + m) * raw[j];
                float Ai = A * inv;
                half8 hv;
#pragma unroll
                for (int c = 0; c < 8; ++c) hv[c] = (_Float16)(Ai * wv[c][j]);
                if (k < LDSC)
                    lds_w[j][k * PTHREADS + tid] = hv;
                else
                    wg[(size_t)j * NGW + (size_t)L * GLOB_GPB +
                       (gl - LDSC * PTHREADS)] = hv;
            }
            bias_r[k] = bout;
        }
    }

    __threadfence();
    grid.sync();   // wg visible (and a clean phase boundary)

    // ---------------- 24 propagation steps --------------------------------
    const float* prev = blur;
    for (int it = 0; it < NITER; ++it) {
        float* nxt = (it == NITER - 1) ? out : ((it & 1) ? r1 : r0);
        const float* pb = prev + (size_t)batch * PLANE;

#pragma unroll
        for (int k = 0; k < NCHUNK; ++k) {
            const int gl = k * PTHREADS + tid;
            if (gl < GPB) {
                const int yo   = gl / GPR;
                const int xg   = gl - yo * GPR;
                const int y    = rowbase + yo;
                const int x0   = 4 * xg;
                const int rowb = y * WW;
                const int pidx = batch * PLANE + rowb + x0;

                half8 hv0, hv1, hv2, hv3;
                if (k < LDSC) {
                    hv0 = lds_w[0][k * PTHREADS + tid];
                    hv1 = lds_w[1][k * PTHREADS + tid];
                    hv2 = lds_w[2][k * PTHREADS + tid];
                    hv3 = lds_w[3][k * PTHREADS + tid];
                } else {
                    const size_t wb = (size_t)L * GLOB_GPB +
                                      (gl - LDSC * PTHREADS);
                    hv0 = wg[0 * NGW + wb];
                    hv1 = wg[1 * NGW + wb];
                    hv2 = wg[2 * NGW + wb];
                    hv3 = wg[3 * NGW + wb];
                }
                f4 acc = bias_r[k];

                if (x0 >= 8 && x0 <= 756) {
                    const int ya = (y >= 5)      ? y - 5 : y;
                    const int yb = (y >= 1)      ? y - 1 : y;
                    const int yc = (y <= HH - 6) ? y + 5 : y;
                    const int yd = (y <= HH - 2) ? y + 1 : y;
                    f4 um5 = sel4(y >= 5,      ldf4(pb + ya * WW + x0));
                    f4 um1 = sel4(y >= 1,      ldf4(pb + yb * WW + x0));
                    f4 dp5 = sel4(y <= HH - 6, ldf4(pb + yc * WW + x0));
                    f4 dp1 = sel4(y <= HH - 2, ldf4(pb + yd * WW + x0));
                    f4 m2 = ldf4(pb + rowb + x0 - 8);
                    f4 m1 = ldf4(pb + rowb + x0 - 4);
                    f4 c0 = ldf4(pb + rowb + x0);
                    f4 p1 = ldf4(pb + rowb + x0 + 4);
                    f4 p2 = ldf4(pb + rowb + x0 + 8);
                    f4 tm5 = f4{m2[3], m1[0], m1[1], m1[2]};   // dx=-5
                    f4 tm1 = f4{m1[3], c0[0], c0[1], c0[2]};   // dx=-1
                    f4 tp1 = f4{c0[1], c0[2], c0[3], p1[0]};   // dx=+1
                    f4 tp5 = f4{p1[1], p1[2], p1[3], p2[0]};   // dx=+5

                    acc[0] = fmaf((float)hv0[0], um5[0], acc[0]);
                    acc[1] = fmaf((float)hv1[0], um5[1], acc[1]);
                    acc[2] = fmaf((float)hv2[0], um5[2], acc[2]);
                    acc[3] = fmaf((float)hv3[0], um5[3], acc[3]);

                    acc[0] = fmaf((float)hv0[1], um1[0], acc[0]);
                    acc[1] = fmaf((float)hv1[1], um1[1], acc[1]);
                    acc[2] = fmaf((float)hv2[1], um1[2], acc[2]);
                    acc[3] = fmaf((float)hv3[1], um1[3], acc[3]);

                    acc[0] = fmaf((float)hv0[2], tp5[0], acc[0]);
                    acc[1] = fmaf((float)hv1[2], tp5[1], acc[1]);
                    acc[2] = fmaf((float)hv2[2], tp5[2], acc[2]);
                    acc[3] = fmaf((float)hv3[2], tp5[3], acc[3]);

                    acc[0] = fmaf((float)hv0[3], tp1[0], acc[0]);
                    acc[1] = fmaf((float)hv1[3], tp1[1], acc[1]);
                    acc[2] = fmaf((float)hv2[3], tp1[2], acc[2]);
                    acc[3] = fmaf((float)hv3[3], tp1[3], acc[3]);

                    acc[0] = fmaf((float)hv0[4], dp5[0], acc[0]);
                    acc[1] = fmaf((float)hv1[4], dp5[1], acc[1]);
                    acc[2] = fmaf((float)hv2[4], dp5[2], acc[2]);
                    acc[3] = fmaf((float)hv3[4], dp5[3], acc[3]);

                    acc[0] = fmaf((float)hv0[5], dp1[0], acc[0]);
                    acc[1] = fmaf((float)hv1[5], dp1[1], acc[1]);
                    acc[2] = fmaf((float)hv2[5], dp1[2], acc[2]);
                    acc[3] = fmaf((float)hv3[5], dp1[3], acc[3]);

                    acc[0] = fmaf((float)hv0[6], tm5[0], acc[0]);
                    acc[1] = fmaf((float)hv1[6], tm5[1], acc[1]);
                    acc[2] = fmaf((float)hv2[6], tm5[2], acc[2]);
                    acc[3] = fmaf((float)hv3[6], tm5[3], acc[3]);

                    acc[0] = fmaf((float)hv0[7], tm1[0], acc[0]);
                    acc[1] = fmaf((float)hv1[7], tm1[1], acc[1]);
                    acc[2] = fmaf((float)hv2[7], tm1[2], acc[2]);
                    acc[3] = fmaf((float)hv3[7], tm1[3], acc[3]);
                } else {
                    const int dy[8] = DYS;
                    const int dx[8] = DXS;
                    half8 hvs[4] = {hv0, hv1, hv2, hv3};
#pragma unroll
                    for (int j = 0; j < 4; ++j) {
#pragma unroll
                        for (int c = 0; c < 8; ++c) {
                            int yy = y + dy[c];
                            int xx = x0 + j + dx[c];
                            float n = 0.f;
                            if (yy >= 0 && yy < HH && xx >= 0 && xx < WW)
                                n = pb[yy * WW + xx];
                            acc[j] = fmaf((float)hvs[j][c], n, acc[j]);
                        }
                    }
                }
                *(f4*)(nxt + pidx) = acc;
            }
        }

        __threadfence();
        grid.sync();
        prev = nxt;
    }
}

// ===========================================================================
// R4 fallback kernels (proven path) — used if cooperative launch unavailable.
// ===========================================================================
__global__ __launch_bounds__(192) void precompute_kernel(
    const float* __restrict__ g,
    const float* __restrict__ blur,
    const float* __restrict__ sparse,
    half8* __restrict__ wout,          // 4 planes x NG half8 (j-plane layout)
    float* __restrict__ bias)
{
    const int x0 = 4 * threadIdx.x;
    const int y  = blockIdx.y;
    const int b  = blockIdx.z;
    const float* gb = g + (size_t)b * 8 * PLANE;
    const int rowb = y * WW;
    const int pidx = b * PLANE + rowb + x0;
    const int pg   = pidx >> 2;

    f4 wv[8];
    if (x0 >= 8 && x0 <= 756) {
        const f4 zero = (f4)0.f;
        wv[0] = (y >= 5)      ? ldf4(gb + 0 * PLANE + (y - 5) * WW + x0) : zero;
        wv[1] = (y >= 1)      ? ldf4(gb + 1 * PLANE + (y - 1) * WW + x0) : zero;
        wv[4] = (y <= HH - 6) ? ldf4(gb + 4 * PLANE + (y + 5) * WW + x0) : zero;
        wv[5] = (y <= HH - 2) ? ldf4(gb + 5 * PLANE + (y + 1) * WW + x0) : zero;
        {   f4 a = ldf4(gb + 2 * PLANE + rowb + x0 + 4);
            f4 bq = ldf4(gb + 2 * PLANE + rowb + x0 + 8);
            wv[2] = f4{a[1], a[2], a[3], bq[0]}; }
        {   f4 a = ldf4(gb + 3 * PLANE + rowb + x0);
            f4 bq = ldf4(gb + 3 * PLANE + rowb + x0 + 4);
            wv[3] = f4{a[1], a[2], a[3], bq[0]}; }
        {   f4 a = ldf4(gb + 6 * PLANE + rowb + x0 - 8);
            f4 bq = ldf4(gb + 6 * PLANE + rowb + x0 - 4);
            wv[6] = f4{a[3], bq[0], bq[1], bq[2]}; }
        {   f4 a = ldf4(gb + 7 * PLANE + rowb + x0 - 4);
            f4 bq = ldf4(gb + 7 * PLANE + rowb + x0);
            wv[7] = f4{a[3], bq[0], bq[1], bq[2]}; }
    } else {
        const int dy[8] = DYS;
        const int dx[8] = DXS;
#pragma unroll
        for (int c = 0; c < 8; ++c) {
#pragma unroll
            for (int j = 0; j < 4; ++j) {
                int yy = y + dy[c];
                int xx = x0 + j + dx[c];
                float v = 0.f;
                if (yy >= 0 && yy < HH && xx >= 0 && xx < WW)
                    v = gb[c * PLANE + yy * WW + xx];
                wv[c][j] = v;
            }
        }
    }

    f4 raw = ldf4(blur + pidx);
    f4 sd  = ldf4(sparse + pidx);
    f4 bout;
#pragma unroll
    for (int j = 0; j < 4; ++j) {
        float abssum = 0.f;
#pragma unroll
        for (int c = 0; c < 8; ++c) abssum += fabsf(wv[c][j]);
        float inv = 1.f / fmaxf(abssum, 1e-6f);
        float gs = 0.f;
#pragma unroll
        for (int c = 0; c < 8; ++c) gs += wv[c][j] * inv;
        float s = sd[j];
        float m = (s > 0.f) ? 1.f : ((s < 0.f) ? -1.f : 0.f);
        float A = 1.f - m;
        bout[j] = (A * (1.f - gs) + m) * raw[j];
        float Ai = A * inv;
        half8 hv;
#pragma unroll
        for (int c = 0; c < 8; ++c) hv[c] = (_Float16)(Ai * wv[c][j]);
        wout[(size_t)j * NG + pg] = hv;
    }
    *(f4*)(bias + pidx) = bout;
}

__global__ __launch_bounds__(192) void step_kernel(
    const half8* __restrict__ w,
    const float* __restrict__ bias,
    const float* __restrict__ prev,
    float* __restrict__ next)
{
    const int L  = blockIdx.x;
    const int b  = L & 7;
    const int y  = L >> 3;
    const int x0 = 4 * threadIdx.x;
    const int rowb = y * WW;
    const int pidx = b * PLANE + rowb + x0;
    const int pg   = pidx >> 2;
    const float* pb = prev + b * PLANE;

    half8 hv0 = w[0 * (size_t)NG + pg];
    half8 hv1 = w[1 * (size_t)NG + pg];
    half8 hv2 = w[2 * (size_t)NG + pg];
    half8 hv3 = w[3 * (size_t)NG + pg];
    f4 acc = ldf4(bias + pidx);

    if (x0 >= 8 && x0 <= 756) {
        const f4 zero = (f4)0.f;
        f4 um5 = (y >= 5)      ? ldf4(pb + (y - 5) * WW + x0) : zero;
        f4 um1 = (y >= 1)      ? ldf4(pb + (y - 1) * WW + x0) : zero;
        f4 dp5 = (y <= HH - 6) ? ldf4(pb + (y + 5) * WW + x0) : zero;
        f4 dp1 = (y <= HH - 2) ? ldf4(pb + (y + 1) * WW + x0) : zero;
        f4 m2 = ldf4(pb + rowb + x0 - 8);
        f4 m1 = ldf4(pb + rowb + x0 - 4);
        f4 c0 = ldf4(pb + rowb + x0);
        f4 p1 = ldf4(pb + rowb + x0 + 4);
        f4 p2 = ldf4(pb + rowb + x0 + 8);
        f4 tm5 = f4{m2[3], m1[0], m1[1], m1[2]};
        f4 tm1 = f4{m1[3], c0[0], c0[1], c0[2]};
        f4 tp1 = f4{c0[1], c0[2], c0[3], p1[0]};
        f4 tp5 = f4{p1[1], p1[2], p1[3], p2[0]};

        acc[0] = fmaf((float)hv0[0], um5[0], acc[0]);
        acc[1] = fmaf((float)hv1[0], um5[1], acc[1]);
        acc[2] = fmaf((float)hv2[0], um5[2], acc[2]);
        acc[3] = fmaf((float)hv3[0], um5[3], acc[3]);
        acc[0] = fmaf((float)hv0[1], um1[0], acc[0]);
        acc[1] = fmaf((float)hv1[1], um1[1], acc[1]);
        acc[2] = fmaf((float)hv2[1], um1[2], acc[2]);
        acc[3] = fmaf((float)hv3[1], um1[3], acc[3]);
        acc[0] = fmaf((float)hv0[2], tp5[0], acc[0]);
        acc[1] = fmaf((float)hv1[2], tp5[1], acc[1]);
        acc[2] = fmaf((float)hv2[2], tp5[2], acc[2]);
        acc[3] = fmaf((float)hv3[2], tp5[3], acc[3]);
        acc[0] = fmaf((float)hv0[3], tp1[0], acc[0]);
        acc[1] = fmaf((float)hv1[3], tp1[1], acc[1]);
        acc[2] = fmaf((float)hv2[3], tp1[2], acc[2]);
        acc[3] = fmaf((float)hv3[3], tp1[3], acc[3]);
        acc[0] = fmaf((float)hv0[4], dp5[0], acc[0]);
        acc[1] = fmaf((float)hv1[4], dp5[1], acc[1]);
        acc[2] = fmaf((float)hv2[4], dp5[2], acc[2]);
        acc[3] = fmaf((float)hv3[4], dp5[3], acc[3]);
        acc[0] = fmaf((float)hv0[5], dp1[0], acc[0]);
        acc[1] = fmaf((float)hv1[5], dp1[1], acc[1]);
        acc[2] = fmaf((float)hv2[5], dp1[2], acc[2]);
        acc[3] = fmaf((float)hv3[5], dp1[3], acc[3]);
        acc[0] = fmaf((float)hv0[6], tm5[0], acc[0]);
        acc[1] = fmaf((float)hv1[6], tm5[1], acc[1]);
        acc[2] = fmaf((float)hv2[6], tm5[2], acc[2]);
        acc[3] = fmaf((float)hv3[6], tm5[3], acc[3]);
        acc[0] = fmaf((float)hv0[7], tm1[0], acc[0]);
        acc[1] = fmaf((float)hv1[7], tm1[1], acc[1]);
        acc[2] = fmaf((float)hv2[7], tm1[2], acc[2]);
        acc[3] = fmaf((float)hv3[7], tm1[3], acc[3]);
    } else {
        const int dy[8] = DYS;
        const int dx[8] = DXS;
        half8 hvs[4] = {hv0, hv1, hv2, hv3};
#pragma unroll
        for (int j = 0; j < 4; ++j) {
#pragma unroll
            for (int c = 0; c < 8; ++c) {
                int yy = y + dy[c];
                int xx = x0 + j + dx[c];
                float n = 0.f;
                if (yy >= 0 && yy < HH && xx >= 0 && xx < WW)
                    n = pb[yy * WW + xx];
                acc[j] = fmaf((float)hvs[j][c], n, acc[j]);
            }
        }
    }
    *(f4*)(next + pidx) = acc;
}

__global__ __launch_bounds__(256) void step_recompute_kernel(
    const float* __restrict__ g,
    const float* __restrict__ blur,
    const float* __restrict__ sparse,
    const float* __restrict__ prev,
    float* __restrict__ next)
{
    const int dy[8] = DYS;
    const int dx[8] = DXS;
    int x = blockIdx.x * blockDim.x + threadIdx.x;
    int y = blockIdx.y;
    int b = blockIdx.z;
    if (x >= WW) return;

    const float* gb = g + (size_t)b * 8 * PLANE;
    float w[8];
    float abssum = 0.f;
#pragma unroll
    for (int c = 0; c < 8; ++c) {
        int yy = y + dy[c];
        int xx = x + dx[c];
        float v = 0.f;
        if (yy >= 0 && yy < HH && xx >= 0 && xx < WW)
            v = gb[c * PLANE + yy * WW + xx];
        w[c] = v;
        abssum += fabsf(v);
    }
    float inv = 1.f / fmaxf(abssum, 1e-6f);
    float gs = 0.f;
#pragma unroll
    for (int c = 0; c < 8; ++c) {
        w[c] *= inv;
        gs += w[c];
    }
    int pidx = b * PLANE + y * WW + x;
    float sd = sparse[pidx];
    float m = (sd > 0.f) ? 1.f : ((sd < 0.f) ? -1.f : 0.f);
    float A = 1.f - m;
    float raw = blur[pidx];

    const float* pb = prev + b * PLANE;
    float acc = 0.f;
#pragma unroll
    for (int c = 0; c < 8; ++c) {
        int yy = y + dy[c];
        int xx = x + dx[c];
        float n = 0.f;
        if (yy >= 0 && yy < HH && xx >= 0 && xx < WW)
            n = pb[yy * WW + xx];
        acc = fmaf(A * w[c], n, acc);
    }
    next[pidx] = acc + (A * (1.f - gs) + m) * raw;
}

// ---------------------------------------------------------------------------
extern "C" void kernel_launch(void* const* d_in, const int* in_sizes, int n_in,
                              void* d_out, int out_size, void* d_ws, size_t ws_size,
                              hipStream_t stream) {
    const float* g      = (const float*)d_in[0];
    const float* blur   = (const float*)d_in[1];
    const float* sparse = (const float*)d_in[2];
    float* out = (float*)d_out;

    // fast-path ws requirement (same gate as R4; persistent needs less)
    const size_t need_fast = (size_t)TOTAL * 16 + (size_t)TOTAL * 4 * 2;

    if (ws_size >= need_fast) {
        // -------- try R5 persistent cooperative path ----------------------
        int maxB = 0;
        hipError_t oe = hipOccupancyMaxActiveBlocksPerMultiprocessor(
            &maxB, persist_kernel, PTHREADS, 0);
        if (oe == hipSuccess && maxB >= 4) {
            const size_t wgBytes = (size_t)4 * NGW * sizeof(half8);  // 41.94 MB
            half8* wg = (half8*)d_ws;
            float* r0 = (float*)((char*)d_ws + wgBytes);
            float* r1 = r0 + TOTAL;

            void* args[7];
            args[0] = (void*)&g;
            args[1] = (void*)&blur;
            args[2] = (void*)&sparse;
            args[3] = (void*)&wg;
            args[4] = (void*)&r0;
            args[5] = (void*)&r1;
            args[6] = (void*)&out;

            hipError_t le = hipLaunchCooperativeKernel(
                (const void*)persist_kernel, dim3(PBLOCKS), dim3(PTHREADS),
                args, 0, stream);
            if (le == hipSuccess) return;
            // else fall through to R4 multi-launch path
        }

        // -------- R4 fallback: precompute + 24 step launches --------------
        dim3 blockPre(192, 1, 1);
        dim3 gridPre(1, HH, BATCH);
        dim3 blockStep(192, 1, 1);
        dim3 gridStep(HH * BATCH, 1, 1);

        half8* w    = (half8*)d_ws;
        float* bias = (float*)((char*)d_ws + (size_t)TOTAL * 16);
        float* r0   = bias + TOTAL;

        precompute_kernel<<<gridPre, blockPre, 0, stream>>>(g, blur, sparse, w, bias);

        const float* prev = blur;
        for (int it = 0; it < NITER; ++it) {
            float* nxt = (it % 2 == 0) ? r0 : out;
            step_kernel<<<gridStep, blockStep, 0, stream>>>(w, bias, prev, nxt);
            prev = nxt;
        }
    } else {
        dim3 block2(256, 1, 1);
        dim3 grid2(WW / 256, HH, BATCH);
        float* r0 = (float*)d_ws;
        const float* prev = blur;
        for (int it = 0; it < NITER; ++it) {
            float* nxt = (it % 2 == 0) ? r0 : out;
            step_recompute_kernel<<<grid2, block2, 0, stream>>>(g, blur, sparse,
                                                                prev, nxt);
            prev = nxt;
        }
    }
}